// Round 4
// baseline (317.020 us; speedup 1.0000x reference)
//
#include <hip/hip_runtime.h>
#include <cstdint>

typedef unsigned short u16;
typedef __attribute__((ext_vector_type(8))) short short8;
typedef __attribute__((ext_vector_type(4))) float f32x4;

#define NTOK 2048
#define CDIM 1024
#define C3   3072
#define NH   8
#define HD   128

__device__ __forceinline__ float bf2f(u16 u) {
    return __uint_as_float(((unsigned)u) << 16);
}
__device__ __forceinline__ u16 f2bf(float f) {
    unsigned u = __float_as_uint(f);
    u += 0x7fffu + ((u >> 16) & 1u);
    return (u16)(u >> 16);
}

// ---------------------------------------------------------------- K1: f32->bf16
__global__ __launch_bounds__(256) void k_cast(const float* __restrict__ x,
                                              const float* __restrict__ w,
                                              u16* __restrict__ xb,
                                              u16* __restrict__ wb) {
    int t = blockIdx.x * blockDim.x + threadIdx.x;
    int stride = gridDim.x * blockDim.x;
    for (int i = t; i < (NTOK * CDIM) / 4; i += stride) {
        float4 v = ((const float4*)x)[i];
        ushort4 o;
        o.x = f2bf(v.x); o.y = f2bf(v.y); o.z = f2bf(v.z); o.w = f2bf(v.w);
        ((ushort4*)xb)[i] = o;
    }
    for (int i = t; i < (C3 * CDIM) / 4; i += stride) {
        float4 v = ((const float4*)w)[i];
        ushort4 o;
        o.x = f2bf(v.x); o.y = f2bf(v.y); o.z = f2bf(v.z); o.w = f2bf(v.w);
        ((ushort4*)wb)[i] = o;
    }
}

// ---------------------------------------------------------------- K2: generic bf16 GEMM, C = A[M,K] @ B[N,K]^T
// EPI 0: write bf16. EPI 1: write u8 (acc*scale > 0.75).
template <int EPI>
__global__ __launch_bounds__(256) void k_gemm_bt(const u16* __restrict__ A,
                                                 const u16* __restrict__ B,
                                                 void* __restrict__ Cv, int K,
                                                 int lda, int ldb, int ldc,
                                                 float scale) {
    __shared__ u16 As[128][40];
    __shared__ u16 Bs[128][40];
    const int tid = threadIdx.x;
    const int lane = tid & 63;
    const int wid = tid >> 6;
    const int wm = wid >> 1, wn = wid & 1;
    const int q = lane >> 4, l16 = lane & 15;
    const int m0 = blockIdx.y * 128, n0 = blockIdx.x * 128;

    f32x4 zero4 = {0.f, 0.f, 0.f, 0.f};
    f32x4 acc[4][4];
#pragma unroll
    for (int i = 0; i < 4; i++)
#pragma unroll
        for (int j = 0; j < 4; j++) acc[i][j] = zero4;

    for (int k0 = 0; k0 < K; k0 += 32) {
        __syncthreads();
        {
            int v = tid;
            int row = v >> 2, kc = (v & 3) * 8;
            *(short8*)&As[row][kc] =
                *(const short8*)&A[(long long)(m0 + row) * lda + k0 + kc];
            *(short8*)&Bs[row][kc] =
                *(const short8*)&B[(long long)(n0 + row) * ldb + k0 + kc];
            v = tid + 256;
            row = v >> 2; kc = (v & 3) * 8;
            *(short8*)&As[row][kc] =
                *(const short8*)&A[(long long)(m0 + row) * lda + k0 + kc];
            *(short8*)&Bs[row][kc] =
                *(const short8*)&B[(long long)(n0 + row) * ldb + k0 + kc];
        }
        __syncthreads();
        short8 af[4], bfr[4];
#pragma unroll
        for (int tm = 0; tm < 4; tm++)
            af[tm] = *(const short8*)&As[wm * 64 + tm * 16 + l16][q * 8];
#pragma unroll
        for (int tn = 0; tn < 4; tn++)
            bfr[tn] = *(const short8*)&Bs[wn * 64 + tn * 16 + l16][q * 8];
#pragma unroll
        for (int tm = 0; tm < 4; tm++)
#pragma unroll
            for (int tn = 0; tn < 4; tn++)
                acc[tm][tn] = __builtin_amdgcn_mfma_f32_16x16x32_bf16(
                    af[tm], bfr[tn], acc[tm][tn], 0, 0, 0);
    }

#pragma unroll
    for (int tm = 0; tm < 4; tm++) {
#pragma unroll
        for (int tn = 0; tn < 4; tn++) {
#pragma unroll
            for (int r = 0; r < 4; r++) {
                int row = m0 + wm * 64 + tm * 16 + q * 4 + r;
                int col = n0 + wn * 64 + tn * 16 + l16;
                float v = acc[tm][tn][r];
                long long off = (long long)row * ldc + col;
                if (EPI == 0) {
                    ((u16*)Cv)[off] = f2bf(v);
                } else {
                    ((unsigned char*)Cv)[off] = (v * scale > 0.75f) ? 1 : 0;
                }
            }
        }
    }
}

// ---------------------------------------------------------------- K3: per-row L2 normalize q/k/v heads + x_ori
__global__ __launch_bounds__(256) void k_norm(const u16* __restrict__ qkv,
                                              u16* __restrict__ Qn,
                                              u16* __restrict__ Kn,
                                              u16* __restrict__ Vn,
                                              float* __restrict__ out) {
    int n = blockIdx.x;
    int lane = threadIdx.x & 63;
    int w = threadIdx.x >> 6;
    for (int s = w; s < 24; s += 4) {
        int which = s >> 3;  // 0=q 1=k 2=v
        int h = s & 7;
        int d0 = lane * 2;
        const u16* src = qkv + (long long)n * C3 + which * CDIM + h * HD + d0;
        u16 u0 = src[0], u1 = src[1];
        float f0 = bf2f(u0), f1 = bf2f(u1);
        float ss = f0 * f0 + f1 * f1;
#pragma unroll
        for (int off = 1; off < 64; off <<= 1) ss += __shfl_xor(ss, off);
        float rn = rsqrtf(ss);
        u16* dst = (which == 0 ? Qn : which == 1 ? Kn : Vn) +
                   (long long)n * CDIM + h * HD + d0;
        ushort2 nv;
        nv.x = f2bf(f0 * rn);
        nv.y = f2bf(f1 * rn);
        *(ushort2*)dst = nv;
        if (which == 2) {
            float2 fo;
            fo.x = f0; fo.y = f1;
            *(float2*)&out[(long long)n * 2048 + 1024 + h * HD + d0] = fo;
        }
    }
}

// ---------------------------------------------------------------- K3b: tiled transpose Vt[c][n] = v[n][c] (raw v)
__global__ __launch_bounds__(256) void k_vt(const u16* __restrict__ qkv,
                                            u16* __restrict__ Vt) {
    __shared__ u16 T[64][72];
    const int n0 = blockIdx.x * 64;
    const int c0 = blockIdx.y * 64;
    const int tid = threadIdx.x;
    {
        int nl = tid >> 2, cc = (tid & 3) * 16;
        const u16* src = &qkv[(long long)(n0 + nl) * C3 + 2 * CDIM + c0 + cc];
        *(short8*)&T[nl][cc] = *(const short8*)&src[0];
        *(short8*)&T[nl][cc + 8] = *(const short8*)&src[8];
    }
    __syncthreads();
    {
        int cl = tid >> 2, nc = (tid & 3) * 16;
        ushort va[16];
#pragma unroll
        for (int i = 0; i < 16; i++) va[i] = T[nc + i][cl];
        u16* dst = &Vt[(long long)(c0 + cl) * NTOK + n0 + nc];
        *(short8*)&dst[0] = *(short8*)&va[0];
        *(short8*)&dst[8] = *(short8*)&va[8];
    }
}

// ---------------------------------------------------------------- K4: fused QK->exp->P + PV, VGPR-prefetch pipeline
// grid (32 i-tiles, 4 j-chunks, 8 heads) = 1024 blocks, LDS 40960 B -> 4 blocks/CU
__global__ __launch_bounds__(256, 4) void k_attn4(const u16* __restrict__ Qn,
                                                  const u16* __restrict__ Kn,
                                                  const u16* __restrict__ Vt,
                                                  const float* __restrict__ cls,
                                                  u16* __restrict__ P,
                                                  float* __restrict__ Spart,
                                                  u16* __restrict__ Xpart) {
    __shared__ u16 Kf[8192];  // QK B-frags, slot ((tn*4+kt)*64+lane)*8
    __shared__ u16 Vf[8192];  // PV B-frags, slot ((n*2+ks)*64+lane)*8
    __shared__ u16 Et[4096];  // e tile 64x64 bf16, XOR-chunk swizzled
    const int h = blockIdx.z;
    const int jc = blockIdx.y;
    const int i0 = blockIdx.x * 64;
    const int jbase = jc * 512;
    const int tid = threadIdx.x, lane = tid & 63, wid = tid >> 6;
    const int q = lane >> 4, l16 = lane & 15;
    const int wm = wid >> 1, wn = wid & 1;

    // resident Q fragments (i range: wm*32 .. +31)
    short8 af[2][4];
#pragma unroll
    for (int m = 0; m < 2; m++)
#pragma unroll
        for (int kt = 0; kt < 4; kt++)
            af[m][kt] = *(const short8*)&Qn[(long long)(i0 + wm * 32 + m * 16 + l16) * CDIM +
                                            h * HD + kt * 32 + q * 8];
    float cls_i[2][4];
#pragma unroll
    for (int m = 0; m < 2; m++)
#pragma unroll
        for (int r = 0; r < 4; r++)
            cls_i[m][r] = cls[i0 + wm * 32 + m * 16 + q * 4 + r] - 0.1f;

    // staging geometry (fixed per thread)
    const int rK = tid >> 2;              // K row within 64-j tile
    const int tnK = rK >> 4, s16K = rK & 15;
    const u16* kptr = &Kn[(long long)(jbase + rK) * CDIM + h * HD + (tid & 3) * 32];
    const int dV = tid >> 1;              // V dim row
    const int jhV = (tid & 1) * 32;
    const int nV = dV >> 4, dlV = dV & 15;
    const u16* vptr = &Vt[(long long)(h * HD + dV) * NTOK + jbase + jhV];

    // prefetch tile 0 into registers
    short8 kpre[4], vpre[4];
#pragma unroll
    for (int c = 0; c < 4; c++) {
        kpre[c] = *(const short8*)&kptr[c * 8];
        vpre[c] = *(const short8*)&vptr[c * 8];
    }

    f32x4 zero4 = {0.f, 0.f, 0.f, 0.f};
    f32x4 pv[2][4];
#pragma unroll
    for (int m = 0; m < 2; m++)
#pragma unroll
        for (int n = 0; n < 4; n++) pv[m][n] = zero4;
    float sums[2][4] = {{0.f, 0.f, 0.f, 0.f}, {0.f, 0.f, 0.f, 0.f}};

    for (int jt = 0; jt < 8; ++jt) {
        const int j0 = jbase + jt * 64;
        __syncthreads();  // previous-iter consumers done with Kf/Vf/Et
        // commit prefetched tile to LDS
#pragma unroll
        for (int i = 0; i < 4; i++) {
            int chunk = (tid & 3) * 4 + i;
            int kt = chunk >> 2, qq = chunk & 3;
            *(short8*)&Kf[((tnK * 4 + kt) * 64 + qq * 16 + s16K) * 8] = kpre[i];
        }
#pragma unroll
        for (int c = 0; c < 4; c++) {
            int jc8 = (jhV >> 3) + c;
            int ks = jc8 >> 2, qq = jc8 & 3;
            *(short8*)&Vf[((nV * 2 + ks) * 64 + qq * 16 + dlV) * 8] = vpre[c];
        }
        __syncthreads();
        // issue next tile's loads (consumed at next iter's ds_write)
        if (jt < 7) {
            const u16* kp2 = kptr + (long long)(jt + 1) * 64 * CDIM;
            const u16* vp2 = vptr + (jt + 1) * 64;
#pragma unroll
            for (int c = 0; c < 4; c++) {
                kpre[c] = *(const short8*)&kp2[c * 8];
                vpre[c] = *(const short8*)&vp2[c * 8];
            }
        }
        // QK -> e -> Et (+ row sums)
#pragma unroll
        for (int tn = 0; tn < 2; tn++) {
            int tng = wn * 2 + tn;
            short8 bfr[4];
#pragma unroll
            for (int kt = 0; kt < 4; kt++)
                bfr[kt] = *(const short8*)&Kf[((tng * 4 + kt) * 64 + lane) * 8];
            int j = j0 + tng * 16 + l16;
            float cj = cls[j];
            float sc = 25.f * cj;
#pragma unroll
            for (int m = 0; m < 2; m++) {
                f32x4 acc = zero4;
#pragma unroll
                for (int kt = 0; kt < 4; kt++)
                    acc = __builtin_amdgcn_mfma_f32_16x16x32_bf16(af[m][kt], bfr[kt],
                                                                  acc, 0, 0, 0);
                int ibase = wm * 32 + m * 16 + q * 4;
#pragma unroll
                for (int r = 0; r < 4; r++) {
                    float mk = (cj > cls_i[m][r]) ? 1.f : 0.f;
                    float e = __expf(acc[r] * sc * mk);
                    sums[m][r] += e;
                    int il = ibase + r;
                    int jl = tng * 16 + l16;
                    Et[il * 64 + ((((jl >> 3) ^ (il & 7)) << 3) | (jl & 7))] = f2bf(e);
                }
            }
        }
        __syncthreads();
        {   // coalesced P store from Et
            int il = tid >> 2, c = tid & 3;
            int x = il & 7;
            short8 e0 = *(const short8*)&Et[il * 64 + (((2 * c) ^ x) << 3)];
            short8 e1 = *(const short8*)&Et[il * 64 + (((2 * c + 1) ^ x) << 3)];
            u16* dst = &P[((long long)(h * NTOK + i0 + il)) * NTOK + j0 + c * 16];
            *(short8*)&dst[0] = e0;
            *(short8*)&dst[8] = e1;
        }
        // PV: A from Et (swizzled), B from Vf; out tile i(64) x d(128)
#pragma unroll
        for (int ks = 0; ks < 2; ks++) {
            short8 a2[2];
#pragma unroll
            for (int m2 = 0; m2 < 2; m2++) {
                int il = wm * 32 + m2 * 16 + l16;
                int ch = ks * 4 + q;
                a2[m2] = *(const short8*)&Et[il * 64 + ((ch ^ (il & 7)) << 3)];
            }
#pragma unroll
            for (int n2 = 0; n2 < 4; n2++) {
                short8 b2 = *(const short8*)&Vf[(((wn * 4 + n2) * 2 + ks) * 64 + lane) * 8];
#pragma unroll
                for (int m2 = 0; m2 < 2; m2++)
                    pv[m2][n2] = __builtin_amdgcn_mfma_f32_16x16x32_bf16(
                        a2[m2], b2, pv[m2][n2], 0, 0, 0);
            }
        }
    }
    // row-sum partials (race-free: one writer per (wn,jc,h,row))
#pragma unroll
    for (int m = 0; m < 2; m++)
#pragma unroll
        for (int r = 0; r < 4; r++) {
            float s = sums[m][r];
            s += __shfl_xor(s, 1);
            s += __shfl_xor(s, 2);
            s += __shfl_xor(s, 4);
            s += __shfl_xor(s, 8);
            if (l16 == 0)
                Spart[((wn * 4 + jc) * NH + h) * NTOK + i0 + wm * 32 + m * 16 + q * 4 + r] = s;
        }
    // store PV partial to this jc's slab (bf16, plain stores, no atomics)
    u16* Xp = Xpart + (long long)jc * NTOK * CDIM;
#pragma unroll
    for (int m2 = 0; m2 < 2; m2++)
#pragma unroll
        for (int n2 = 0; n2 < 4; n2++)
#pragma unroll
            for (int r = 0; r < 4; r++) {
                int i = i0 + wm * 32 + m2 * 16 + q * 4 + r;
                int d = wn * 64 + n2 * 16 + l16;
                Xp[(long long)i * CDIM + h * HD + d] = f2bf(pv[m2][n2][r]);
            }
}

// ---------------------------------------------------------------- K5: x = (sum_jc Xpart)/Srow -> out cols [0,1024)
__global__ __launch_bounds__(256) void k_comb2(const u16* __restrict__ Xpart,
                                               const float* __restrict__ Spart,
                                               float* __restrict__ out) {
    int idx = blockIdx.x * 256 + threadIdx.x;  // 262144 threads, 8 elems each
    int base = idx * 8;
    int i = base >> 10, c = base & 1023;
    int h = c >> 7;
    float s = 0.f;
#pragma unroll
    for (int g = 0; g < 8; g++) s += Spart[(g * NH + h) * NTOK + i];
    float acc[8] = {0.f, 0.f, 0.f, 0.f, 0.f, 0.f, 0.f, 0.f};
#pragma unroll
    for (int jc = 0; jc < 4; jc++) {
        short8 v = *(const short8*)&Xpart[(long long)jc * NTOK * CDIM + (long long)i * CDIM + c];
#pragma unroll
        for (int k = 0; k < 8; k++) acc[k] += bf2f((u16)v[k]);
    }
    float invs = 1.f / s;
    float4 o0, o1;
    o0.x = acc[0] * invs; o0.y = acc[1] * invs; o0.z = acc[2] * invs; o0.w = acc[3] * invs;
    o1.x = acc[4] * invs; o1.y = acc[5] * invs; o1.z = acc[6] * invs; o1.w = acc[7] * invs;
    float* dst = &out[(long long)i * 2048 + c];
    *(float4*)dst = o0;
    *(float4*)(dst + 4) = o1;
}

// ---------------------------------------------------------------- K6: output2 = renormed masked softmax of head-mean attn
__global__ __launch_bounds__(256) void k_out2(const u16* __restrict__ P,
                                              const float* __restrict__ Spart,
                                              const unsigned char* __restrict__ mask,
                                              float* __restrict__ out2) {
    __shared__ float red[256];
    __shared__ float sArr[NH];
    const int i = blockIdx.x;
    const int t = threadIdx.x;
    if (t < NH) {
        float s = 0.f;
#pragma unroll
        for (int g = 0; g < 8; g++) s += Spart[(g * NH + t) * NTOK + i];
        sArr[t] = s;
    }
    __syncthreads();
    float invS[NH];
#pragma unroll
    for (int h = 0; h < NH; h++) invS[h] = 1.f / (8.f * sArr[h]);
    const int c0 = t * 8;
    float a[8] = {0.f, 0.f, 0.f, 0.f, 0.f, 0.f, 0.f, 0.f};
#pragma unroll
    for (int h = 0; h < NH; h++) {
        short8 p = *(const short8*)&P[((long long)h * NTOK + i) * NTOK + c0];
#pragma unroll
        for (int k = 0; k < 8; k++) a[k] += bf2f((u16)p[k]) * invS[h];
    }
    const unsigned char* mrow = mask + (long long)i * NTOK + c0;
    float e[8];
    unsigned char mk[8];
    float part = 0.f;
#pragma unroll
    for (int k = 0; k < 8; k++) {
        e[k] = __expf(a[k]);
        mk[k] = mrow[k];
        if (mk[k]) part += e[k];
    }
    red[t] = part;
    __syncthreads();
    for (int s = 128; s > 0; s >>= 1) {
        if (t < s) red[t] += red[t + s];
        __syncthreads();
    }
    float invT = 1.f / red[0];
    float o[8];
#pragma unroll
    for (int k = 0; k < 8; k++) o[k] = mk[k] ? e[k] * invT : 0.f;
    float4 o0, o1;
    o0.x = o[0]; o0.y = o[1]; o0.z = o[2]; o0.w = o[3];
    o1.x = o[4]; o1.y = o[5]; o1.z = o[6]; o1.w = o[7];
    float* dst = out2 + (long long)i * NTOK + c0;
    *(float4*)dst = o0;
    *(float4*)(dst + 4) = o1;
}

// ---------------------------------------------------------------- launcher
extern "C" void kernel_launch(void* const* d_in, const int* in_sizes, int n_in,
                              void* d_out, int out_size, void* d_ws,
                              size_t ws_size, hipStream_t stream) {
    (void)in_sizes; (void)n_in; (void)out_size; (void)ws_size;
    const float* x = (const float*)d_in[0];
    const float* cls = (const float*)d_in[1];
    // d_in[2] = fg_score: unused by the reference
    const float* Wq = (const float*)d_in[3];
    float* out = (float*)d_out;
    char* ws = (char*)d_ws;

    // Region [0, 23068672): early buffers (dead before k_attn4) overlaid with
    // late buffers (written by k_attn4 after the early ones are dead).
    u16* Xb = (u16*)(ws + 0);                      //  4 MB  [2048,1024] (dead after QKV gemm)
    u16* Wb = (u16*)(ws + 4194304);                //  6 MB  [3072,1024] (dead after QKV gemm)
    u16* QKVb = (u16*)(ws + 10485760);             // 12.6MB [2048,3072] (dead after k_vt)
    u16* Xpart = (u16*)(ws + 0);                   // 16 MB  [4][2048,1024] bf16 PV partials
    float* Spart = (float*)(ws + 16777216);        // 512 KB [8][8,2048] row-sum partials
    u16* Qn = (u16*)(ws + 23068672);               //  4 MB
    u16* Kn = (u16*)(ws + 27262976);               //  4 MB
    u16* Vn = (u16*)(ws + 31457280);               //  4 MB
    u16* Vt = (u16*)(ws + 35651584);               //  4 MB  [1024,2048]
    unsigned char* mask = (unsigned char*)(ws + 39845888);  // 4 MB [2048,2048]
    u16* P = (u16*)(ws + 44040192);                // 67 MB [8,2048,2048]

    // 1. cast x and W to bf16
    k_cast<<<1024, 256, 0, stream>>>(x, Wq, Xb, Wb);

    // 2. QKV = Xb @ Wb^T  -> bf16 [2048,3072]
    k_gemm_bt<0><<<dim3(C3 / 128, NTOK / 128), 256, 0, stream>>>(
        Xb, Wb, QKVb, CDIM, CDIM, CDIM, C3, 1.f);

    // 3. normalize q/k/v, write x_ori
    k_norm<<<NTOK, 256, 0, stream>>>(QKVb, Qn, Kn, Vn, out);

    // 3b. Vt = v^T (raw v), tiled transpose
    k_vt<<<dim3(NTOK / 64, CDIM / 64), 256, 0, stream>>>(QKVb, Vt);

    // 4. sim mask = (Vn @ Vn^T / 8 > 0.75) -> u8
    k_gemm_bt<1><<<dim3(16, 16), 256, 0, stream>>>(
        Vn, Vn, mask, CDIM, CDIM, CDIM, NTOK, 0.125f);

    // 5. fused logits+exp -> P, partial row sums, partial PV -> Xpart
    k_attn4<<<dim3(32, 4, NH), 256, 0, stream>>>(Qn, Kn, Vt, cls, P, Spart, Xpart);

    // 5b. x = (sum Xpart) / (sum Spart)
    k_comb2<<<1024, 256, 0, stream>>>(Xpart, Spart, out);

    // 6. output2
    k_out2<<<NTOK, 256, 0, stream>>>(P, Spart, mask, out + (long long)NTOK * 2048);
}

// Round 5
// 279.428 us; speedup vs baseline: 1.1345x; 1.1345x over previous
//
#include <hip/hip_runtime.h>
#include <cstdint>

typedef unsigned short u16;
typedef __attribute__((ext_vector_type(8))) short short8;
typedef __attribute__((ext_vector_type(4))) float f32x4;

#define NTOK 2048
#define CDIM 1024
#define C3   3072
#define NH   8
#define HD   128

__device__ __forceinline__ float bf2f(u16 u) {
    return __uint_as_float(((unsigned)u) << 16);
}
__device__ __forceinline__ u16 f2bf(float f) {
    unsigned u = __float_as_uint(f);
    u += 0x7fffu + ((u >> 16) & 1u);
    return (u16)(u >> 16);
}

// ---------------------------------------------------------------- K1: f32->bf16
__global__ __launch_bounds__(256) void k_cast(const float* __restrict__ x,
                                              const float* __restrict__ w,
                                              u16* __restrict__ xb,
                                              u16* __restrict__ wb) {
    int t = blockIdx.x * blockDim.x + threadIdx.x;
    int stride = gridDim.x * blockDim.x;
    for (int i = t; i < (NTOK * CDIM) / 4; i += stride) {
        float4 v = ((const float4*)x)[i];
        ushort4 o;
        o.x = f2bf(v.x); o.y = f2bf(v.y); o.z = f2bf(v.z); o.w = f2bf(v.w);
        ((ushort4*)xb)[i] = o;
    }
    for (int i = t; i < (C3 * CDIM) / 4; i += stride) {
        float4 v = ((const float4*)w)[i];
        ushort4 o;
        o.x = f2bf(v.x); o.y = f2bf(v.y); o.z = f2bf(v.z); o.w = f2bf(v.w);
        ((ushort4*)wb)[i] = o;
    }
}

// ---------------------------------------------------------------- K2: generic bf16 GEMM, C = A[M,K] @ B[N,K]^T
// EPI 0: write bf16. EPI 1: write u8 (acc*scale > 0.75).
template <int EPI>
__global__ __launch_bounds__(256) void k_gemm_bt(const u16* __restrict__ A,
                                                 const u16* __restrict__ B,
                                                 void* __restrict__ Cv, int K,
                                                 int lda, int ldb, int ldc,
                                                 float scale) {
    __shared__ u16 As[128][40];
    __shared__ u16 Bs[128][40];
    const int tid = threadIdx.x;
    const int lane = tid & 63;
    const int wid = tid >> 6;
    const int wm = wid >> 1, wn = wid & 1;
    const int q = lane >> 4, l16 = lane & 15;
    const int m0 = blockIdx.y * 128, n0 = blockIdx.x * 128;

    f32x4 zero4 = {0.f, 0.f, 0.f, 0.f};
    f32x4 acc[4][4];
#pragma unroll
    for (int i = 0; i < 4; i++)
#pragma unroll
        for (int j = 0; j < 4; j++) acc[i][j] = zero4;

    for (int k0 = 0; k0 < K; k0 += 32) {
        __syncthreads();
        {
            int v = tid;
            int row = v >> 2, kc = (v & 3) * 8;
            *(short8*)&As[row][kc] =
                *(const short8*)&A[(long long)(m0 + row) * lda + k0 + kc];
            *(short8*)&Bs[row][kc] =
                *(const short8*)&B[(long long)(n0 + row) * ldb + k0 + kc];
            v = tid + 256;
            row = v >> 2; kc = (v & 3) * 8;
            *(short8*)&As[row][kc] =
                *(const short8*)&A[(long long)(m0 + row) * lda + k0 + kc];
            *(short8*)&Bs[row][kc] =
                *(const short8*)&B[(long long)(n0 + row) * ldb + k0 + kc];
        }
        __syncthreads();
        short8 af[4], bfr[4];
#pragma unroll
        for (int tm = 0; tm < 4; tm++)
            af[tm] = *(const short8*)&As[wm * 64 + tm * 16 + l16][q * 8];
#pragma unroll
        for (int tn = 0; tn < 4; tn++)
            bfr[tn] = *(const short8*)&Bs[wn * 64 + tn * 16 + l16][q * 8];
#pragma unroll
        for (int tm = 0; tm < 4; tm++)
#pragma unroll
            for (int tn = 0; tn < 4; tn++)
                acc[tm][tn] = __builtin_amdgcn_mfma_f32_16x16x32_bf16(
                    af[tm], bfr[tn], acc[tm][tn], 0, 0, 0);
    }

#pragma unroll
    for (int tm = 0; tm < 4; tm++) {
#pragma unroll
        for (int tn = 0; tn < 4; tn++) {
#pragma unroll
            for (int r = 0; r < 4; r++) {
                int row = m0 + wm * 64 + tm * 16 + q * 4 + r;
                int col = n0 + wn * 64 + tn * 16 + l16;
                float v = acc[tm][tn][r];
                long long off = (long long)row * ldc + col;
                if (EPI == 0) {
                    ((u16*)Cv)[off] = f2bf(v);
                } else {
                    ((unsigned char*)Cv)[off] = (v * scale > 0.75f) ? 1 : 0;
                }
            }
        }
    }
}

// ---------------------------------------------------------------- K3: per-row L2 normalize q/k/v heads + x_ori
__global__ __launch_bounds__(256) void k_norm(const u16* __restrict__ qkv,
                                              u16* __restrict__ Qn,
                                              u16* __restrict__ Kn,
                                              u16* __restrict__ Vn,
                                              float* __restrict__ out) {
    int n = blockIdx.x;
    int lane = threadIdx.x & 63;
    int w = threadIdx.x >> 6;
    for (int s = w; s < 24; s += 4) {
        int which = s >> 3;  // 0=q 1=k 2=v
        int h = s & 7;
        int d0 = lane * 2;
        const u16* src = qkv + (long long)n * C3 + which * CDIM + h * HD + d0;
        u16 u0 = src[0], u1 = src[1];
        float f0 = bf2f(u0), f1 = bf2f(u1);
        float ss = f0 * f0 + f1 * f1;
#pragma unroll
        for (int off = 1; off < 64; off <<= 1) ss += __shfl_xor(ss, off);
        float rn = rsqrtf(ss);
        u16* dst = (which == 0 ? Qn : which == 1 ? Kn : Vn) +
                   (long long)n * CDIM + h * HD + d0;
        ushort2 nv;
        nv.x = f2bf(f0 * rn);
        nv.y = f2bf(f1 * rn);
        *(ushort2*)dst = nv;
        if (which == 2) {
            float2 fo;
            fo.x = f0; fo.y = f1;
            *(float2*)&out[(long long)n * 2048 + 1024 + h * HD + d0] = fo;
        }
    }
}

// ---------------------------------------------------------------- K3b: tiled transpose Vt[c][n] = v[n][c] (raw v)
__global__ __launch_bounds__(256) void k_vt(const u16* __restrict__ qkv,
                                            u16* __restrict__ Vt) {
    __shared__ u16 T[64][72];
    const int n0 = blockIdx.x * 64;
    const int c0 = blockIdx.y * 64;
    const int tid = threadIdx.x;
    {
        int nl = tid >> 2, cc = (tid & 3) * 16;
        const u16* src = &qkv[(long long)(n0 + nl) * C3 + 2 * CDIM + c0 + cc];
        *(short8*)&T[nl][cc] = *(const short8*)&src[0];
        *(short8*)&T[nl][cc + 8] = *(const short8*)&src[8];
    }
    __syncthreads();
    {
        int cl = tid >> 2, nc = (tid & 3) * 16;
        ushort va[16];
#pragma unroll
        for (int i = 0; i < 16; i++) va[i] = T[nc + i][cl];
        u16* dst = &Vt[(long long)(c0 + cl) * NTOK + n0 + nc];
        *(short8*)&dst[0] = *(short8*)&va[0];
        *(short8*)&dst[8] = *(short8*)&va[8];
    }
}

// ---------------------------------------------------------------- K4: fused QK->exp->P + PV, 32x32 tiles, 8 blocks/CU
// grid (64 i-tiles, 4 j-chunks, 8 heads) = 2048 blocks; LDS 18432 B -> 8 blocks/CU
__global__ __launch_bounds__(256, 8) void k_attn5(const u16* __restrict__ Qn,
                                                  const u16* __restrict__ Kn,
                                                  const u16* __restrict__ Vt,
                                                  const float* __restrict__ cls,
                                                  u16* __restrict__ P,
                                                  float* __restrict__ Spart,
                                                  u16* __restrict__ Xpart) {
    __shared__ u16 Kf[4096];  // QK B-frags: 8 groups (tn*4+kt) x 64 lanes x 8
    __shared__ u16 Vf[4096];  // PV B-frags: 8 groups (n)        x 64 lanes x 8
    __shared__ u16 Et[1024];  // e tile 32x32 bf16, XOR-chunk swizzled (4 chunks/row)
    const int h = blockIdx.z;
    const int jc = blockIdx.y;
    const int i0 = blockIdx.x * 32;
    const int jbase = jc * 512;
    const int tid = threadIdx.x, lane = tid & 63, wid = tid >> 6;
    const int q = lane >> 4, l16 = lane & 15;
    const int wm = wid >> 1, wn = wid & 1;

    // resident Q fragments: A row = i0 + wm*16 + l16
    short8 af[4];
#pragma unroll
    for (int kt = 0; kt < 4; kt++)
        af[kt] = *(const short8*)&Qn[(long long)(i0 + wm * 16 + l16) * CDIM +
                                     h * HD + kt * 32 + q * 8];
    float cls_i[4];
#pragma unroll
    for (int r = 0; r < 4; r++) cls_i[r] = cls[i0 + wm * 16 + q * 4 + r] - 0.1f;

    // staging geometry
    const int rowK = tid >> 3;            // 0..31 (j row in tile)
    const int colK = (tid & 7) * 16;      // 0..112 (c within head slice)
    const u16* kptr = &Kn[(long long)(jbase + rowK) * CDIM + h * HD + colK];
    const int tnK = rowK >> 4, s16K = rowK & 15;
    const int cc0 = colK >> 3;            // even chunk index 0..14
    const int dV = tid >> 1;              // 0..127 (d row)
    const int jjV = (tid & 1) * 16;       // 0 or 16
    const u16* vptr = &Vt[(long long)(h * HD + dV) * NTOK + jbase + jjV];
    const int nV = dV >> 4, dlV = dV & 15;
    const int q0V = jjV >> 3;             // 0 or 2

    f32x4 zero4 = {0.f, 0.f, 0.f, 0.f};
    f32x4 pv[4];
#pragma unroll
    for (int n = 0; n < 4; n++) pv[n] = zero4;
    float sums[4] = {0.f, 0.f, 0.f, 0.f};

    for (int jt = 0; jt < 16; ++jt) {
        const int j0 = jbase + jt * 32;
        __syncthreads();  // prev-iter consumers done with Kf/Vf/Et
        {   // stage K tile (32 j x 128 c), fragment-ready
            const u16* kp = kptr + (long long)jt * 32 * CDIM;
            short8 a = *(const short8*)&kp[0];
            short8 b = *(const short8*)&kp[8];
            int kt0 = cc0 >> 2, qq0 = cc0 & 3;
            int cc1 = cc0 + 1, kt1 = cc1 >> 2, qq1 = cc1 & 3;
            *(short8*)&Kf[((tnK * 4 + kt0) * 64 + qq0 * 16 + s16K) * 8] = a;
            *(short8*)&Kf[((tnK * 4 + kt1) * 64 + qq1 * 16 + s16K) * 8] = b;
        }
        {   // stage V tile (128 d x 32 j), fragment-ready
            const u16* vp = vptr + jt * 32;
            short8 a = *(const short8*)&vp[0];
            short8 b = *(const short8*)&vp[8];
            *(short8*)&Vf[(nV * 64 + q0V * 16 + dlV) * 8] = a;
            *(short8*)&Vf[(nV * 64 + (q0V + 1) * 16 + dlV) * 8] = b;
        }
        __syncthreads();
        // QK: wave (wm,wn) -> out tile rows wm*16.., cols wn*16..
        {
            short8 bfr[4];
#pragma unroll
            for (int kt = 0; kt < 4; kt++)
                bfr[kt] = *(const short8*)&Kf[((wn * 4 + kt) * 64 + lane) * 8];
            int j = j0 + wn * 16 + l16;
            float cj = cls[j];
            float sc = 25.f * cj;
            f32x4 acc = zero4;
#pragma unroll
            for (int kt = 0; kt < 4; kt++)
                acc = __builtin_amdgcn_mfma_f32_16x16x32_bf16(af[kt], bfr[kt], acc,
                                                              0, 0, 0);
            int jl = wn * 16 + l16;
#pragma unroll
            for (int r = 0; r < 4; r++) {
                int il = wm * 16 + q * 4 + r;
                float mk = (cj > cls_i[r]) ? 1.f : 0.f;
                float e = __expf(acc[r] * sc * mk);
                sums[r] += e;
                Et[il * 32 + (((jl >> 3) ^ (il & 3)) << 3) + (jl & 7)] = f2bf(e);
            }
        }
        __syncthreads();
        if (tid < 128) {  // coalesced P store from Et
            int il = tid >> 2, c = tid & 3;
            short8 e0 = *(const short8*)&Et[il * 32 + ((c ^ (il & 3)) << 3)];
            *(short8*)&P[((long long)(h * NTOK + i0 + il)) * NTOK + j0 + c * 8] = e0;
        }
        // PV: A from Et (row = wm*16+l16, k-chunk = q), B from Vf
        {
            int il = wm * 16 + l16;
            short8 a2 = *(const short8*)&Et[il * 32 + ((q ^ (il & 3)) << 3)];
#pragma unroll
            for (int n2 = 0; n2 < 4; n2++) {
                short8 b2 = *(const short8*)&Vf[((wn * 4 + n2) * 64 + lane) * 8];
                pv[n2] = __builtin_amdgcn_mfma_f32_16x16x32_bf16(a2, b2, pv[n2],
                                                                 0, 0, 0);
            }
        }
    }
    // row-sum partials (one writer per (wn,jc,h,row))
#pragma unroll
    for (int r = 0; r < 4; r++) {
        float s = sums[r];
        s += __shfl_xor(s, 1);
        s += __shfl_xor(s, 2);
        s += __shfl_xor(s, 4);
        s += __shfl_xor(s, 8);
        if (l16 == 0)
            Spart[((wn * 4 + jc) * NH + h) * NTOK + i0 + wm * 16 + q * 4 + r] = s;
    }
    // PV partial to this jc's slab (bf16, plain stores)
    u16* Xp = Xpart + (long long)jc * NTOK * CDIM;
#pragma unroll
    for (int n2 = 0; n2 < 4; n2++)
#pragma unroll
        for (int r = 0; r < 4; r++) {
            int i = i0 + wm * 16 + q * 4 + r;
            int d = wn * 64 + n2 * 16 + l16;
            Xp[(long long)i * CDIM + h * HD + d] = f2bf(pv[n2][r]);
        }
}

// ---------------------------------------------------------------- K5: x = (sum_jc Xpart)/Srow -> out cols [0,1024)
__global__ __launch_bounds__(256) void k_comb2(const u16* __restrict__ Xpart,
                                               const float* __restrict__ Spart,
                                               float* __restrict__ out) {
    int idx = blockIdx.x * 256 + threadIdx.x;
    int base = idx * 8;
    int i = base >> 10, c = base & 1023;
    int h = c >> 7;
    float s = 0.f;
#pragma unroll
    for (int g = 0; g < 8; g++) s += Spart[(g * NH + h) * NTOK + i];
    float acc[8] = {0.f, 0.f, 0.f, 0.f, 0.f, 0.f, 0.f, 0.f};
#pragma unroll
    for (int jc = 0; jc < 4; jc++) {
        short8 v = *(const short8*)&Xpart[(long long)jc * NTOK * CDIM + (long long)i * CDIM + c];
#pragma unroll
        for (int k = 0; k < 8; k++) acc[k] += bf2f((u16)v[k]);
    }
    float invs = 1.f / s;
    float4 o0, o1;
    o0.x = acc[0] * invs; o0.y = acc[1] * invs; o0.z = acc[2] * invs; o0.w = acc[3] * invs;
    o1.x = acc[4] * invs; o1.y = acc[5] * invs; o1.z = acc[6] * invs; o1.w = acc[7] * invs;
    float* dst = &out[(long long)i * 2048 + c];
    *(float4*)dst = o0;
    *(float4*)(dst + 4) = o1;
}

// ---------------------------------------------------------------- K6: output2 = renormed masked softmax of head-mean attn
__global__ __launch_bounds__(256) void k_out2(const u16* __restrict__ P,
                                              const float* __restrict__ Spart,
                                              const unsigned char* __restrict__ mask,
                                              float* __restrict__ out2) {
    __shared__ float red[256];
    __shared__ float sArr[NH];
    const int i = blockIdx.x;
    const int t = threadIdx.x;
    if (t < NH) {
        float s = 0.f;
#pragma unroll
        for (int g = 0; g < 8; g++) s += Spart[(g * NH + t) * NTOK + i];
        sArr[t] = s;
    }
    __syncthreads();
    float invS[NH];
#pragma unroll
    for (int h = 0; h < NH; h++) invS[h] = 1.f / (8.f * sArr[h]);
    const int c0 = t * 8;
    float a[8] = {0.f, 0.f, 0.f, 0.f, 0.f, 0.f, 0.f, 0.f};
#pragma unroll
    for (int h = 0; h < NH; h++) {
        short8 p = *(const short8*)&P[((long long)h * NTOK + i) * NTOK + c0];
#pragma unroll
        for (int k = 0; k < 8; k++) a[k] += bf2f((u16)p[k]) * invS[h];
    }
    const unsigned char* mrow = mask + (long long)i * NTOK + c0;
    float e[8];
    unsigned char mk[8];
    float part = 0.f;
#pragma unroll
    for (int k = 0; k < 8; k++) {
        e[k] = __expf(a[k]);
        mk[k] = mrow[k];
        if (mk[k]) part += e[k];
    }
    red[t] = part;
    __syncthreads();
    for (int s = 128; s > 0; s >>= 1) {
        if (t < s) red[t] += red[t + s];
        __syncthreads();
    }
    float invT = 1.f / red[0];
    float o[8];
#pragma unroll
    for (int k = 0; k < 8; k++) o[k] = mk[k] ? e[k] * invT : 0.f;
    float4 o0, o1;
    o0.x = o[0]; o0.y = o[1]; o0.z = o[2]; o0.w = o[3];
    o1.x = o[4]; o1.y = o[5]; o1.z = o[6]; o1.w = o[7];
    float* dst = out2 + (long long)i * NTOK + c0;
    *(float4*)dst = o0;
    *(float4*)(dst + 4) = o1;
}

// ---------------------------------------------------------------- launcher
extern "C" void kernel_launch(void* const* d_in, const int* in_sizes, int n_in,
                              void* d_out, int out_size, void* d_ws,
                              size_t ws_size, hipStream_t stream) {
    (void)in_sizes; (void)n_in; (void)out_size; (void)ws_size;
    const float* x = (const float*)d_in[0];
    const float* cls = (const float*)d_in[1];
    // d_in[2] = fg_score: unused by the reference
    const float* Wq = (const float*)d_in[3];
    float* out = (float*)d_out;
    char* ws = (char*)d_ws;

    // Region [0, 23068672): early buffers (dead before k_attn5) overlaid with
    // late buffers (written by k_attn5 after the early ones are dead).
    u16* Xb = (u16*)(ws + 0);                      //  4 MB  [2048,1024] (dead after QKV gemm)
    u16* Wb = (u16*)(ws + 4194304);                //  6 MB  [3072,1024] (dead after QKV gemm)
    u16* QKVb = (u16*)(ws + 10485760);             // 12.6MB [2048,3072] (dead after k_vt)
    u16* Xpart = (u16*)(ws + 0);                   // 16 MB  [4][2048,1024] bf16 PV partials
    float* Spart = (float*)(ws + 16777216);        // 512 KB [8][8,2048] row-sum partials
    u16* Qn = (u16*)(ws + 23068672);               //  4 MB
    u16* Kn = (u16*)(ws + 27262976);               //  4 MB
    u16* Vn = (u16*)(ws + 31457280);               //  4 MB
    u16* Vt = (u16*)(ws + 35651584);               //  4 MB  [1024,2048]
    unsigned char* mask = (unsigned char*)(ws + 39845888);  // 4 MB [2048,2048]
    u16* P = (u16*)(ws + 44040192);                // 67 MB [8,2048,2048]

    // 1. cast x and W to bf16
    k_cast<<<1024, 256, 0, stream>>>(x, Wq, Xb, Wb);

    // 2. QKV = Xb @ Wb^T  -> bf16 [2048,3072]
    k_gemm_bt<0><<<dim3(C3 / 128, NTOK / 128), 256, 0, stream>>>(
        Xb, Wb, QKVb, CDIM, CDIM, CDIM, C3, 1.f);

    // 3. normalize q/k/v, write x_ori
    k_norm<<<NTOK, 256, 0, stream>>>(QKVb, Qn, Kn, Vn, out);

    // 3b. Vt = v^T (raw v), tiled transpose
    k_vt<<<dim3(NTOK / 64, CDIM / 64), 256, 0, stream>>>(QKVb, Vt);

    // 4. sim mask = (Vn @ Vn^T / 8 > 0.75) -> u8
    k_gemm_bt<1><<<dim3(16, 16), 256, 0, stream>>>(
        Vn, Vn, mask, CDIM, CDIM, CDIM, NTOK, 0.125f);

    // 5. fused logits+exp -> P, partial row sums, partial PV -> Xpart
    k_attn5<<<dim3(64, 4, NH), 256, 0, stream>>>(Qn, Kn, Vt, cls, P, Spart, Xpart);

    // 5b. x = (sum Xpart) / (sum Spart)
    k_comb2<<<1024, 256, 0, stream>>>(Xpart, Spart, out);

    // 6. output2
    k_out2<<<NTOK, 256, 0, stream>>>(P, Spart, mask, out + (long long)NTOK * 2048);
}

// Round 6
// 246.442 us; speedup vs baseline: 1.2864x; 1.1338x over previous
//
#include <hip/hip_runtime.h>
#include <cstdint>

typedef unsigned short u16;
typedef __attribute__((ext_vector_type(8))) short short8;
typedef __attribute__((ext_vector_type(4))) float f32x4;

#define NTOK 2048
#define CDIM 1024
#define C3   3072
#define NH   8
#define HD   128

__device__ __forceinline__ float bf2f(u16 u) {
    return __uint_as_float(((unsigned)u) << 16);
}
__device__ __forceinline__ u16 f2bf(float f) {
    unsigned u = __float_as_uint(f);
    u += 0x7fffu + ((u >> 16) & 1u);
    return (u16)(u >> 16);
}

// ---------------------------------------------------------------- K1: QKV GEMM, f32 inputs cast to bf16 in staging
// C[2048,3072] bf16 = A[2048,1024]f32 @ B[3072,1024]f32 ^T
__global__ __launch_bounds__(256) void k_qkv(const float* __restrict__ A,
                                             const float* __restrict__ B,
                                             u16* __restrict__ C) {
    __shared__ u16 As[128][40];
    __shared__ u16 Bs[128][40];
    const int tid = threadIdx.x;
    const int lane = tid & 63;
    const int wid = tid >> 6;
    const int wm = wid >> 1, wn = wid & 1;
    const int q = lane >> 4, l16 = lane & 15;
    const int m0 = blockIdx.y * 128, n0 = blockIdx.x * 128;

    f32x4 zero4 = {0.f, 0.f, 0.f, 0.f};
    f32x4 acc[4][4];
#pragma unroll
    for (int i = 0; i < 4; i++)
#pragma unroll
        for (int j = 0; j < 4; j++) acc[i][j] = zero4;

    const int r = tid >> 1, c0 = (tid & 1) * 16;
    for (int k0 = 0; k0 < CDIM; k0 += 32) {
        __syncthreads();
        {
            const float* a = &A[(long long)(m0 + r) * CDIM + k0 + c0];
            const float* b = &B[(long long)(n0 + r) * CDIM + k0 + c0];
#pragma unroll
            for (int c = 0; c < 4; c++) {
                float4 fa = *(const float4*)&a[c * 4];
                float4 fb = *(const float4*)&b[c * 4];
                ushort4 ua, ub;
                ua.x = f2bf(fa.x); ua.y = f2bf(fa.y); ua.z = f2bf(fa.z); ua.w = f2bf(fa.w);
                ub.x = f2bf(fb.x); ub.y = f2bf(fb.y); ub.z = f2bf(fb.z); ub.w = f2bf(fb.w);
                *(ushort4*)&As[r][c0 + c * 4] = ua;
                *(ushort4*)&Bs[r][c0 + c * 4] = ub;
            }
        }
        __syncthreads();
        short8 af[4], bfr[4];
#pragma unroll
        for (int tm = 0; tm < 4; tm++)
            af[tm] = *(const short8*)&As[wm * 64 + tm * 16 + l16][q * 8];
#pragma unroll
        for (int tn = 0; tn < 4; tn++)
            bfr[tn] = *(const short8*)&Bs[wn * 64 + tn * 16 + l16][q * 8];
#pragma unroll
        for (int tm = 0; tm < 4; tm++)
#pragma unroll
            for (int tn = 0; tn < 4; tn++)
                acc[tm][tn] = __builtin_amdgcn_mfma_f32_16x16x32_bf16(
                    af[tm], bfr[tn], acc[tm][tn], 0, 0, 0);
    }

#pragma unroll
    for (int tm = 0; tm < 4; tm++)
#pragma unroll
        for (int tn = 0; tn < 4; tn++)
#pragma unroll
            for (int r2 = 0; r2 < 4; r2++) {
                int row = m0 + wm * 64 + tm * 16 + q * 4 + r2;
                int col = n0 + wn * 64 + tn * 16 + l16;
                C[(long long)row * C3 + col] = f2bf(acc[tm][tn][r2]);
            }
}

// ---------------------------------------------------------------- K2: bf16 GEMM, mask epilogue (acc*scale > 0.75 -> u8)
__global__ __launch_bounds__(256) void k_gemm_mask(const u16* __restrict__ A,
                                                   const u16* __restrict__ B,
                                                   unsigned char* __restrict__ Cv,
                                                   int K, int lda, int ldb, int ldc,
                                                   float scale) {
    __shared__ u16 As[128][40];
    __shared__ u16 Bs[128][40];
    const int tid = threadIdx.x;
    const int lane = tid & 63;
    const int wid = tid >> 6;
    const int wm = wid >> 1, wn = wid & 1;
    const int q = lane >> 4, l16 = lane & 15;
    const int m0 = blockIdx.y * 128, n0 = blockIdx.x * 128;

    f32x4 zero4 = {0.f, 0.f, 0.f, 0.f};
    f32x4 acc[4][4];
#pragma unroll
    for (int i = 0; i < 4; i++)
#pragma unroll
        for (int j = 0; j < 4; j++) acc[i][j] = zero4;

    for (int k0 = 0; k0 < K; k0 += 32) {
        __syncthreads();
        {
            int v = tid;
            int row = v >> 2, kc = (v & 3) * 8;
            *(short8*)&As[row][kc] =
                *(const short8*)&A[(long long)(m0 + row) * lda + k0 + kc];
            *(short8*)&Bs[row][kc] =
                *(const short8*)&B[(long long)(n0 + row) * ldb + k0 + kc];
            v = tid + 256;
            row = v >> 2; kc = (v & 3) * 8;
            *(short8*)&As[row][kc] =
                *(const short8*)&A[(long long)(m0 + row) * lda + k0 + kc];
            *(short8*)&Bs[row][kc] =
                *(const short8*)&B[(long long)(n0 + row) * ldb + k0 + kc];
        }
        __syncthreads();
        short8 af[4], bfr[4];
#pragma unroll
        for (int tm = 0; tm < 4; tm++)
            af[tm] = *(const short8*)&As[wm * 64 + tm * 16 + l16][q * 8];
#pragma unroll
        for (int tn = 0; tn < 4; tn++)
            bfr[tn] = *(const short8*)&Bs[wn * 64 + tn * 16 + l16][q * 8];
#pragma unroll
        for (int tm = 0; tm < 4; tm++)
#pragma unroll
            for (int tn = 0; tn < 4; tn++)
                acc[tm][tn] = __builtin_amdgcn_mfma_f32_16x16x32_bf16(
                    af[tm], bfr[tn], acc[tm][tn], 0, 0, 0);
    }

#pragma unroll
    for (int tm = 0; tm < 4; tm++)
#pragma unroll
        for (int tn = 0; tn < 4; tn++)
#pragma unroll
            for (int r = 0; r < 4; r++) {
                int row = m0 + wm * 64 + tm * 16 + q * 4 + r;
                int col = n0 + wn * 64 + tn * 16 + l16;
                Cv[(long long)row * ldc + col] =
                    (acc[tm][tn][r] * scale > 0.75f) ? 1 : 0;
            }
}

// ---------------------------------------------------------------- K3: per-row L2 normalize q/k/v heads + x_ori
__global__ __launch_bounds__(256) void k_norm(const u16* __restrict__ qkv,
                                              u16* __restrict__ Qn,
                                              u16* __restrict__ Kn,
                                              u16* __restrict__ Vn,
                                              float* __restrict__ out) {
    int n = blockIdx.x;
    int lane = threadIdx.x & 63;
    int w = threadIdx.x >> 6;
    for (int s = w; s < 24; s += 4) {
        int which = s >> 3;  // 0=q 1=k 2=v
        int h = s & 7;
        int d0 = lane * 2;
        const u16* src = qkv + (long long)n * C3 + which * CDIM + h * HD + d0;
        u16 u0 = src[0], u1 = src[1];
        float f0 = bf2f(u0), f1 = bf2f(u1);
        float ss = f0 * f0 + f1 * f1;
#pragma unroll
        for (int off = 1; off < 64; off <<= 1) ss += __shfl_xor(ss, off);
        float rn = rsqrtf(ss);
        u16* dst = (which == 0 ? Qn : which == 1 ? Kn : Vn) +
                   (long long)n * CDIM + h * HD + d0;
        ushort2 nv;
        nv.x = f2bf(f0 * rn);
        nv.y = f2bf(f1 * rn);
        *(ushort2*)dst = nv;
        if (which == 2) {
            float2 fo;
            fo.x = f0; fo.y = f1;
            *(float2*)&out[(long long)n * 2048 + 1024 + h * HD + d0] = fo;
        }
    }
}

// ---------------------------------------------------------------- K3b: tiled transpose Vt[c][n] = v[n][c] (raw v)
__global__ __launch_bounds__(256) void k_vt(const u16* __restrict__ qkv,
                                            u16* __restrict__ Vt) {
    __shared__ u16 T[64][72];
    const int n0 = blockIdx.x * 64;
    const int c0 = blockIdx.y * 64;
    const int tid = threadIdx.x;
    {
        int nl = tid >> 2, cc = (tid & 3) * 16;
        const u16* src = &qkv[(long long)(n0 + nl) * C3 + 2 * CDIM + c0 + cc];
        *(short8*)&T[nl][cc] = *(const short8*)&src[0];
        *(short8*)&T[nl][cc + 8] = *(const short8*)&src[8];
    }
    __syncthreads();
    {
        int cl = tid >> 2, nc = (tid & 3) * 16;
        ushort va[16];
#pragma unroll
        for (int i = 0; i < 16; i++) va[i] = T[nc + i][cl];
        u16* dst = &Vt[(long long)(c0 + cl) * NTOK + n0 + nc];
        *(short8*)&dst[0] = *(short8*)&va[0];
        *(short8*)&dst[8] = *(short8*)&va[8];
    }
}

// ---------------------------------------------------------------- K4: fused QK->exp->P + PV (R3 geometry, plain stores)
// grid (32 i-tiles, 4 j-chunks, 8 heads) = 1024 blocks; LDS 40960 B -> 4 blocks/CU
__global__ __launch_bounds__(256, 4) void k_attn6(const u16* __restrict__ Qn,
                                                  const u16* __restrict__ Kn,
                                                  const u16* __restrict__ Vt,
                                                  const float* __restrict__ cls,
                                                  u16* __restrict__ P,
                                                  float* __restrict__ Spart,
                                                  u16* __restrict__ Xpart) {
    __shared__ u16 Kf[8192];  // QK B-frags, slot ((tn*4+kt)*64+lane)*8
    __shared__ u16 Vf[8192];  // PV B-frags, slot ((n*2+ks)*64+lane)*8
    __shared__ u16 Et[4096];  // e tile 64x64 bf16, XOR-chunk swizzled
    const int h = blockIdx.z;
    const int jc = blockIdx.y;
    const int i0 = blockIdx.x * 64;
    const int jbase = jc * 512;
    const int tid = threadIdx.x, lane = tid & 63, wid = tid >> 6;
    const int q = lane >> 4, l16 = lane & 15;
    const int wm = wid >> 1, wn = wid & 1;

    // resident Q fragments (i range: wm*32 .. +31)
    short8 af[2][4];
#pragma unroll
    for (int m = 0; m < 2; m++)
#pragma unroll
        for (int kt = 0; kt < 4; kt++)
            af[m][kt] = *(const short8*)&Qn[(long long)(i0 + wm * 32 + m * 16 + l16) * CDIM +
                                            h * HD + kt * 32 + q * 8];
    float cls_i[2][4];
#pragma unroll
    for (int m = 0; m < 2; m++)
#pragma unroll
        for (int r = 0; r < 4; r++)
            cls_i[m][r] = cls[i0 + wm * 32 + m * 16 + q * 4 + r] - 0.1f;

    f32x4 zero4 = {0.f, 0.f, 0.f, 0.f};
    f32x4 pv[2][4];
#pragma unroll
    for (int m = 0; m < 2; m++)
#pragma unroll
        for (int n = 0; n < 4; n++) pv[m][n] = zero4;
    float sums[2][4] = {{0.f, 0.f, 0.f, 0.f}, {0.f, 0.f, 0.f, 0.f}};

    for (int jt = 0; jt < 8; ++jt) {
        const int j0 = jbase + jt * 64;
        __syncthreads();  // previous-iter consumers done with Kf/Vf/Et
        {   // stage K tile (64 j-rows x 128 c) fragment-ready
            int r = tid >> 2;
            int tn = r >> 4, s16 = r & 15;
            const u16* src = &Kn[(long long)(j0 + r) * CDIM + h * HD + (tid & 3) * 32];
#pragma unroll
            for (int i = 0; i < 4; i++) {
                int chunk = (tid & 3) * 4 + i;
                int kt = chunk >> 2, qq = chunk & 3;
                *(short8*)&Kf[((tn * 4 + kt) * 64 + qq * 16 + s16) * 8] =
                    *(const short8*)&src[i * 8];
            }
        }
        {   // stage V tile (128 d x 64 j) fragment-ready from Vt
            int d = tid >> 1;
            int jh = (tid & 1) * 32;
            const u16* src = &Vt[(long long)(h * HD + d) * NTOK + j0 + jh];
            int n = d >> 4, dl = d & 15;
#pragma unroll
            for (int c = 0; c < 4; c++) {
                int jc8 = (jh >> 3) + c;
                int ks = jc8 >> 2, qq = jc8 & 3;
                *(short8*)&Vf[((n * 2 + ks) * 64 + qq * 16 + dl) * 8] =
                    *(const short8*)&src[c * 8];
            }
        }
        __syncthreads();
        // QK -> e -> Et (+ row sums)
#pragma unroll
        for (int tn = 0; tn < 2; tn++) {
            int tng = wn * 2 + tn;
            short8 bfr[4];
#pragma unroll
            for (int kt = 0; kt < 4; kt++)
                bfr[kt] = *(const short8*)&Kf[((tng * 4 + kt) * 64 + lane) * 8];
            int j = j0 + tng * 16 + l16;
            float cj = cls[j];
            float sc = 25.f * cj;
#pragma unroll
            for (int m = 0; m < 2; m++) {
                f32x4 acc = zero4;
#pragma unroll
                for (int kt = 0; kt < 4; kt++)
                    acc = __builtin_amdgcn_mfma_f32_16x16x32_bf16(af[m][kt], bfr[kt],
                                                                  acc, 0, 0, 0);
                int ibase = wm * 32 + m * 16 + q * 4;
#pragma unroll
                for (int r = 0; r < 4; r++) {
                    float mk = (cj > cls_i[m][r]) ? 1.f : 0.f;
                    float e = __expf(acc[r] * sc * mk);
                    sums[m][r] += e;
                    int il = ibase + r;
                    int jl = tng * 16 + l16;
                    Et[il * 64 + ((((jl >> 3) ^ (il & 7)) << 3) | (jl & 7))] = f2bf(e);
                }
            }
        }
        __syncthreads();
        {   // coalesced P store from Et
            int il = tid >> 2, c = tid & 3;
            int x = il & 7;
            short8 e0 = *(const short8*)&Et[il * 64 + (((2 * c) ^ x) << 3)];
            short8 e1 = *(const short8*)&Et[il * 64 + (((2 * c + 1) ^ x) << 3)];
            u16* dst = &P[((long long)(h * NTOK + i0 + il)) * NTOK + j0 + c * 16];
            *(short8*)&dst[0] = e0;
            *(short8*)&dst[8] = e1;
        }
        // PV: A from Et (swizzled), B from Vf; out tile i(64) x d(128)
#pragma unroll
        for (int ks = 0; ks < 2; ks++) {
            short8 a2[2];
#pragma unroll
            for (int m2 = 0; m2 < 2; m2++) {
                int il = wm * 32 + m2 * 16 + l16;
                int ch = ks * 4 + q;
                a2[m2] = *(const short8*)&Et[il * 64 + ((ch ^ (il & 7)) << 3)];
            }
#pragma unroll
            for (int n2 = 0; n2 < 4; n2++) {
                short8 b2 = *(const short8*)&Vf[(((wn * 4 + n2) * 2 + ks) * 64 + lane) * 8];
#pragma unroll
                for (int m2 = 0; m2 < 2; m2++)
                    pv[m2][n2] = __builtin_amdgcn_mfma_f32_16x16x32_bf16(
                        a2[m2], b2, pv[m2][n2], 0, 0, 0);
            }
        }
    }
    // row-sum partials (race-free: one writer per (wn,jc,h,row))
#pragma unroll
    for (int m = 0; m < 2; m++)
#pragma unroll
        for (int r = 0; r < 4; r++) {
            float s = sums[m][r];
            s += __shfl_xor(s, 1);
            s += __shfl_xor(s, 2);
            s += __shfl_xor(s, 4);
            s += __shfl_xor(s, 8);
            if (l16 == 0)
                Spart[((wn * 4 + jc) * NH + h) * NTOK + i0 + wm * 32 + m * 16 + q * 4 + r] = s;
        }
    // store PV partial to this jc's slab (bf16, plain stores, no atomics)
    u16* Xp = Xpart + (long long)jc * NTOK * CDIM;
#pragma unroll
    for (int m2 = 0; m2 < 2; m2++)
#pragma unroll
        for (int n2 = 0; n2 < 4; n2++)
#pragma unroll
            for (int r = 0; r < 4; r++) {
                int i = i0 + wm * 32 + m2 * 16 + q * 4 + r;
                int d = wn * 64 + n2 * 16 + l16;
                Xp[(long long)i * CDIM + h * HD + d] = f2bf(pv[m2][n2][r]);
            }
}

// ---------------------------------------------------------------- K5: x = (sum_jc Xpart)/Srow -> out cols [0,1024)
__global__ __launch_bounds__(256) void k_comb2(const u16* __restrict__ Xpart,
                                               const float* __restrict__ Spart,
                                               float* __restrict__ out) {
    int idx = blockIdx.x * 256 + threadIdx.x;
    int base = idx * 8;
    int i = base >> 10, c = base & 1023;
    int h = c >> 7;
    float s = 0.f;
#pragma unroll
    for (int g = 0; g < 8; g++) s += Spart[(g * NH + h) * NTOK + i];
    float acc[8] = {0.f, 0.f, 0.f, 0.f, 0.f, 0.f, 0.f, 0.f};
#pragma unroll
    for (int jc = 0; jc < 4; jc++) {
        short8 v = *(const short8*)&Xpart[(long long)jc * NTOK * CDIM + (long long)i * CDIM + c];
#pragma unroll
        for (int k = 0; k < 8; k++) acc[k] += bf2f((u16)v[k]);
    }
    float invs = 1.f / s;
    float4 o0, o1;
    o0.x = acc[0] * invs; o0.y = acc[1] * invs; o0.z = acc[2] * invs; o0.w = acc[3] * invs;
    o1.x = acc[4] * invs; o1.y = acc[5] * invs; o1.z = acc[6] * invs; o1.w = acc[7] * invs;
    float* dst = &out[(long long)i * 2048 + c];
    *(float4*)dst = o0;
    *(float4*)(dst + 4) = o1;
}

// ---------------------------------------------------------------- K6: output2 = renormed masked softmax of head-mean attn
__global__ __launch_bounds__(256) void k_out2(const u16* __restrict__ P,
                                              const float* __restrict__ Spart,
                                              const unsigned char* __restrict__ mask,
                                              float* __restrict__ out2) {
    __shared__ float red[256];
    __shared__ float sArr[NH];
    const int i = blockIdx.x;
    const int t = threadIdx.x;
    if (t < NH) {
        float s = 0.f;
#pragma unroll
        for (int g = 0; g < 8; g++) s += Spart[(g * NH + t) * NTOK + i];
        sArr[t] = s;
    }
    __syncthreads();
    float invS[NH];
#pragma unroll
    for (int h = 0; h < NH; h++) invS[h] = 1.f / (8.f * sArr[h]);
    const int c0 = t * 8;
    float a[8] = {0.f, 0.f, 0.f, 0.f, 0.f, 0.f, 0.f, 0.f};
#pragma unroll
    for (int h = 0; h < NH; h++) {
        short8 p = *(const short8*)&P[((long long)h * NTOK + i) * NTOK + c0];
#pragma unroll
        for (int k = 0; k < 8; k++) a[k] += bf2f((u16)p[k]) * invS[h];
    }
    const unsigned char* mrow = mask + (long long)i * NTOK + c0;
    float e[8];
    unsigned char mk[8];
    float part = 0.f;
#pragma unroll
    for (int k = 0; k < 8; k++) {
        e[k] = __expf(a[k]);
        mk[k] = mrow[k];
        if (mk[k]) part += e[k];
    }
    red[t] = part;
    __syncthreads();
    for (int s = 128; s > 0; s >>= 1) {
        if (t < s) red[t] += red[t + s];
        __syncthreads();
    }
    float invT = 1.f / red[0];
    float o[8];
#pragma unroll
    for (int k = 0; k < 8; k++) o[k] = mk[k] ? e[k] * invT : 0.f;
    float4 o0, o1;
    o0.x = o[0]; o0.y = o[1]; o0.z = o[2]; o0.w = o[3];
    o1.x = o[4]; o1.y = o[5]; o1.z = o[6]; o1.w = o[7];
    float* dst = out2 + (long long)i * NTOK + c0;
    *(float4*)dst = o0;
    *(float4*)(dst + 4) = o1;
}

// ---------------------------------------------------------------- launcher
extern "C" void kernel_launch(void* const* d_in, const int* in_sizes, int n_in,
                              void* d_out, int out_size, void* d_ws,
                              size_t ws_size, hipStream_t stream) {
    (void)in_sizes; (void)n_in; (void)out_size; (void)ws_size;
    const float* x = (const float*)d_in[0];
    const float* cls = (const float*)d_in[1];
    // d_in[2] = fg_score: unused by the reference
    const float* Wq = (const float*)d_in[3];
    float* out = (float*)d_out;
    char* ws = (char*)d_ws;

    // Region [0, 23068672): QKVb (early, dead after k_vt) overlaid with
    // Xpart/Spart (written by k_attn6 only after QKVb is dead).
    u16* QKVb = (u16*)(ws + 10485760);             // 12.6MB [2048,3072]
    u16* Xpart = (u16*)(ws + 0);                   // 16 MB  [4][2048,1024] bf16 PV partials
    float* Spart = (float*)(ws + 16777216);        // 512 KB [8][8,2048] row-sum partials
    u16* Qn = (u16*)(ws + 23068672);               //  4 MB
    u16* Kn = (u16*)(ws + 27262976);               //  4 MB
    u16* Vn = (u16*)(ws + 31457280);               //  4 MB
    u16* Vt = (u16*)(ws + 35651584);               //  4 MB  [1024,2048]
    unsigned char* mask = (unsigned char*)(ws + 39845888);  // 4 MB [2048,2048]
    u16* P = (u16*)(ws + 44040192);                // 67 MB [8,2048,2048]

    // 1. QKV = x @ W^T (f32 in, bf16 staged, bf16 out)
    k_qkv<<<dim3(C3 / 128, NTOK / 128), 256, 0, stream>>>(x, Wq, QKVb);

    // 2. normalize q/k/v, write x_ori
    k_norm<<<NTOK, 256, 0, stream>>>(QKVb, Qn, Kn, Vn, out);

    // 2b. Vt = v^T (raw v), tiled transpose
    k_vt<<<dim3(NTOK / 64, CDIM / 64), 256, 0, stream>>>(QKVb, Vt);

    // 3. sim mask = (Vn @ Vn^T / 8 > 0.75) -> u8
    k_gemm_mask<<<dim3(16, 16), 256, 0, stream>>>(
        Vn, Vn, mask, CDIM, CDIM, CDIM, NTOK, 0.125f);

    // 4. fused logits+exp -> P, partial row sums, partial PV -> Xpart
    k_attn6<<<dim3(32, 4, NH), 256, 0, stream>>>(Qn, Kn, Vt, cls, P, Spart, Xpart);

    // 5. x = (sum Xpart) / (sum Spart)
    k_comb2<<<1024, 256, 0, stream>>>(Xpart, Spart, out);

    // 6. output2
    k_out2<<<NTOK, 256, 0, stream>>>(P, Spart, mask, out + (long long)NTOK * 2048);
}

// Round 7
// 222.373 us; speedup vs baseline: 1.4256x; 1.1082x over previous
//
#include <hip/hip_runtime.h>
#include <cstdint>

typedef unsigned short u16;
typedef __attribute__((ext_vector_type(8))) short short8;
typedef __attribute__((ext_vector_type(4))) float f32x4;

#define NTOK 2048
#define CDIM 1024
#define C3   3072
#define NH   8
#define HD   128

__device__ __forceinline__ float bf2f(u16 u) {
    return __uint_as_float(((unsigned)u) << 16);
}
__device__ __forceinline__ u16 f2bf(float f) {
    unsigned u = __float_as_uint(f);
    u += 0x7fffu + ((u >> 16) & 1u);
    return (u16)(u >> 16);
}
// async 16B global->LDS DMA; LDS dest must be wave-uniform base + lane*16
__device__ __forceinline__ void gld_lds16(const u16* g, u16* l) {
    __builtin_amdgcn_global_load_lds(
        (__attribute__((address_space(1))) void*)(u16*)g,
        (__attribute__((address_space(3))) void*)l, 16, 0, 0);
}

// ---------------------------------------------------------------- K0: f32->bf16
__global__ __launch_bounds__(256) void k_cast(const float* __restrict__ x,
                                              const float* __restrict__ w,
                                              u16* __restrict__ xb,
                                              u16* __restrict__ wb) {
    int t = blockIdx.x * blockDim.x + threadIdx.x;
    int stride = gridDim.x * blockDim.x;
    for (int i = t; i < (NTOK * CDIM) / 4; i += stride) {
        float4 v = ((const float4*)x)[i];
        ushort4 o;
        o.x = f2bf(v.x); o.y = f2bf(v.y); o.z = f2bf(v.z); o.w = f2bf(v.w);
        ((ushort4*)xb)[i] = o;
    }
    for (int i = t; i < (C3 * CDIM) / 4; i += stride) {
        float4 v = ((const float4*)w)[i];
        ushort4 o;
        o.x = f2bf(v.x); o.y = f2bf(v.y); o.z = f2bf(v.z); o.w = f2bf(v.w);
        ((ushort4*)wb)[i] = o;
    }
}

// ---------------------------------------------------------------- K1: m97-style bf16 GEMM, C = A[M,K] @ B[N,K]^T
// global_load_lds staging, unpadded [128][32] LDS tiles, 2 barriers/k-step.
// EPI 0: write bf16. EPI 1: write u8 (acc*scale > 0.75).
template <int EPI>
__global__ __launch_bounds__(256) void k_gemm16(const u16* __restrict__ A,
                                                const u16* __restrict__ B,
                                                void* __restrict__ Cv, int K,
                                                int lda, int ldb, int ldc,
                                                float scale) {
    __shared__ u16 As[128 * 32];
    __shared__ u16 Bs[128 * 32];
    const int tid = threadIdx.x;
    const int lane = tid & 63;
    const int wid = tid >> 6;
    const int wm = wid >> 1, wn = wid & 1;
    const int q = lane >> 4, l16 = lane & 15;
    const int m0 = blockIdx.y * 128, n0 = blockIdx.x * 128;

    f32x4 zero4 = {0.f, 0.f, 0.f, 0.f};
    f32x4 acc[4][4];
#pragma unroll
    for (int i = 0; i < 4; i++)
#pragma unroll
        for (int j = 0; j < 4; j++) acc[i][j] = zero4;

    // slot s (0..511): row = s>>2, 8-u16 chunk = s&3.  s = tid and tid+256
    // keeps LDS dest = wave-uniform base + lane*16.
    const int s0 = tid, r0 = s0 >> 2, c0 = (s0 & 3) * 8;
    const int s1 = tid + 256, r1 = s1 >> 2, c1 = (s1 & 3) * 8;
    const u16* a0 = &A[(long long)(m0 + r0) * lda + c0];
    const u16* b0 = &B[(long long)(n0 + r0) * ldb + c0];
    const u16* a1 = &A[(long long)(m0 + r1) * lda + c1];
    const u16* b1 = &B[(long long)(n0 + r1) * ldb + c1];

    for (int k0 = 0; k0 < K; k0 += 32) {
        __syncthreads();
        gld_lds16(a0 + k0, &As[s0 * 8]);
        gld_lds16(b0 + k0, &Bs[s0 * 8]);
        gld_lds16(a1 + k0, &As[s1 * 8]);
        gld_lds16(b1 + k0, &Bs[s1 * 8]);
        __syncthreads();
        short8 af[4], bfr[4];
#pragma unroll
        for (int tm = 0; tm < 4; tm++)
            af[tm] = *(const short8*)&As[(wm * 64 + tm * 16 + l16) * 32 + q * 8];
#pragma unroll
        for (int tn = 0; tn < 4; tn++)
            bfr[tn] = *(const short8*)&Bs[(wn * 64 + tn * 16 + l16) * 32 + q * 8];
#pragma unroll
        for (int tm = 0; tm < 4; tm++)
#pragma unroll
            for (int tn = 0; tn < 4; tn++)
                acc[tm][tn] = __builtin_amdgcn_mfma_f32_16x16x32_bf16(
                    af[tm], bfr[tn], acc[tm][tn], 0, 0, 0);
    }

#pragma unroll
    for (int tm = 0; tm < 4; tm++)
#pragma unroll
        for (int tn = 0; tn < 4; tn++)
#pragma unroll
            for (int r = 0; r < 4; r++) {
                int row = m0 + wm * 64 + tm * 16 + q * 4 + r;
                int col = n0 + wn * 64 + tn * 16 + l16;
                float v = acc[tm][tn][r];
                long long off = (long long)row * ldc + col;
                if (EPI == 0) {
                    ((u16*)Cv)[off] = f2bf(v);
                } else {
                    ((unsigned char*)Cv)[off] = (v * scale > 0.75f) ? 1 : 0;
                }
            }
}

// ---------------------------------------------------------------- K3: per-row L2 normalize q/k/v heads + x_ori
__global__ __launch_bounds__(256) void k_norm(const u16* __restrict__ qkv,
                                              u16* __restrict__ Qn,
                                              u16* __restrict__ Kn,
                                              u16* __restrict__ Vn,
                                              float* __restrict__ out) {
    int n = blockIdx.x;
    int lane = threadIdx.x & 63;
    int w = threadIdx.x >> 6;
    for (int s = w; s < 24; s += 4) {
        int which = s >> 3;  // 0=q 1=k 2=v
        int h = s & 7;
        int d0 = lane * 2;
        const u16* src = qkv + (long long)n * C3 + which * CDIM + h * HD + d0;
        u16 u0 = src[0], u1 = src[1];
        float f0 = bf2f(u0), f1 = bf2f(u1);
        float ss = f0 * f0 + f1 * f1;
#pragma unroll
        for (int off = 1; off < 64; off <<= 1) ss += __shfl_xor(ss, off);
        float rn = rsqrtf(ss);
        u16* dst = (which == 0 ? Qn : which == 1 ? Kn : Vn) +
                   (long long)n * CDIM + h * HD + d0;
        ushort2 nv;
        nv.x = f2bf(f0 * rn);
        nv.y = f2bf(f1 * rn);
        *(ushort2*)dst = nv;
        if (which == 2) {
            float2 fo;
            fo.x = f0; fo.y = f1;
            *(float2*)&out[(long long)n * 2048 + 1024 + h * HD + d0] = fo;
        }
    }
}

// ---------------------------------------------------------------- K3b: tiled transpose Vt[c][n] = v[n][c] (raw v)
__global__ __launch_bounds__(256) void k_vt(const u16* __restrict__ qkv,
                                            u16* __restrict__ Vt) {
    __shared__ u16 T[64][72];
    const int n0 = blockIdx.x * 64;
    const int c0 = blockIdx.y * 64;
    const int tid = threadIdx.x;
    {
        int nl = tid >> 2, cc = (tid & 3) * 16;
        const u16* src = &qkv[(long long)(n0 + nl) * C3 + 2 * CDIM + c0 + cc];
        *(short8*)&T[nl][cc] = *(const short8*)&src[0];
        *(short8*)&T[nl][cc + 8] = *(const short8*)&src[8];
    }
    __syncthreads();
    {
        int cl = tid >> 2, nc = (tid & 3) * 16;
        ushort va[16];
#pragma unroll
        for (int i = 0; i < 16; i++) va[i] = T[nc + i][cl];
        u16* dst = &Vt[(long long)(c0 + cl) * NTOK + n0 + nc];
        *(short8*)&dst[0] = *(short8*)&va[0];
        *(short8*)&dst[8] = *(short8*)&va[8];
    }
}

// ---------------------------------------------------------------- K4: fused QK->exp->P + PV, DMA staging
// grid (32 i-tiles, 4 j-chunks, 8 heads) = 1024 blocks; LDS 40960 B -> 4 blocks/CU
__global__ __launch_bounds__(256, 4) void k_attn7(const u16* __restrict__ Qn,
                                                  const u16* __restrict__ Kn,
                                                  const u16* __restrict__ Vt,
                                                  const float* __restrict__ cls,
                                                  u16* __restrict__ P,
                                                  float* __restrict__ Spart,
                                                  u16* __restrict__ Xpart) {
    __shared__ u16 Kf[16384];  // QK B-frags, 16 groups: slot ((tn*4+kt)*64+lane)*8
    __shared__ u16 Vf[16384];  // PV B-frags, 16 groups: slot ((n*2+ks)*64+lane)*8
    __shared__ u16 Et[4096];   // e tile 64x64 bf16, XOR-chunk swizzled
    const int h = blockIdx.z;
    const int jc = blockIdx.y;
    const int i0 = blockIdx.x * 64;
    const int jbase = jc * 512;
    const int tid = threadIdx.x, lane = tid & 63, wid = tid >> 6;
    const int q = lane >> 4, l16 = lane & 15;
    const int wm = wid >> 1, wn = wid & 1;

    // resident Q fragments (i range: wm*32 .. +31)
    short8 af[2][4];
#pragma unroll
    for (int m = 0; m < 2; m++)
#pragma unroll
        for (int kt = 0; kt < 4; kt++)
            af[m][kt] = *(const short8*)&Qn[(long long)(i0 + wm * 32 + m * 16 + l16) * CDIM +
                                            h * HD + kt * 32 + q * 8];
    float cls_i[2][4];
#pragma unroll
    for (int m = 0; m < 2; m++)
#pragma unroll
        for (int r = 0; r < 4; r++)
            cls_i[m][r] = cls[i0 + wm * 32 + m * 16 + q * 4 + r] - 0.1f;

    // DMA gather sources: wave `wid` owns groups wid*4..wid*4+3 for Kf and Vf.
    // Kf group g=(tn*4+kt): lane l -> Kn[(j0+tn*16+l16)*CDIM + h*HD + kt*32 + q*8]
    // Vf group g=(n*2+ks):  lane l -> Vt[(h*HD + n*16+l16)*NTOK + j0 + (ks*4+q)*8]
    const u16* ksrc[4];
    const u16* vsrc[4];
#pragma unroll
    for (int t = 0; t < 4; t++) {
        int g = wid * 4 + t;
        int tn = g >> 2, kt = g & 3;
        ksrc[t] = &Kn[(long long)(jbase + tn * 16 + l16) * CDIM + h * HD + kt * 32 + q * 8];
        int n = g >> 1, ks = g & 1;
        vsrc[t] = &Vt[(long long)(h * HD + n * 16 + l16) * NTOK + jbase + (ks * 4 + q) * 8];
    }

    f32x4 zero4 = {0.f, 0.f, 0.f, 0.f};
    f32x4 pv[2][4];
#pragma unroll
    for (int m = 0; m < 2; m++)
#pragma unroll
        for (int n = 0; n < 4; n++) pv[m][n] = zero4;
    float sums[2][4] = {{0.f, 0.f, 0.f, 0.f}, {0.f, 0.f, 0.f, 0.f}};

    for (int jt = 0; jt < 8; ++jt) {
        const int j0 = jbase + jt * 64;
        __syncthreads();  // previous-iter consumers done with Kf/Vf/Et
#pragma unroll
        for (int t = 0; t < 4; t++) {
            int g = wid * 4 + t;
            gld_lds16(ksrc[t], &Kf[(g * 64 + lane) * 8]);
            gld_lds16(vsrc[t], &Vf[(g * 64 + lane) * 8]);
            ksrc[t] += 64 * CDIM;
            vsrc[t] += 64;
        }
        __syncthreads();  // drains DMA (vmcnt) + LDS visible
        // QK -> e -> Et (+ row sums)
#pragma unroll
        for (int tn = 0; tn < 2; tn++) {
            int tng = wn * 2 + tn;
            short8 bfr[4];
#pragma unroll
            for (int kt = 0; kt < 4; kt++)
                bfr[kt] = *(const short8*)&Kf[((tng * 4 + kt) * 64 + lane) * 8];
            int j = j0 + tng * 16 + l16;
            float cj = cls[j];
            float sc = 25.f * cj;
#pragma unroll
            for (int m = 0; m < 2; m++) {
                f32x4 acc = zero4;
#pragma unroll
                for (int kt = 0; kt < 4; kt++)
                    acc = __builtin_amdgcn_mfma_f32_16x16x32_bf16(af[m][kt], bfr[kt],
                                                                  acc, 0, 0, 0);
                int ibase = wm * 32 + m * 16 + q * 4;
#pragma unroll
                for (int r = 0; r < 4; r++) {
                    float mk = (cj > cls_i[m][r]) ? 1.f : 0.f;
                    float e = __expf(acc[r] * sc * mk);
                    sums[m][r] += e;
                    int il = ibase + r;
                    int jl = tng * 16 + l16;
                    Et[il * 64 + ((((jl >> 3) ^ (il & 7)) << 3) | (jl & 7))] = f2bf(e);
                }
            }
        }
        __syncthreads();
        {   // coalesced P store from Et
            int il = tid >> 2, c = tid & 3;
            int x = il & 7;
            short8 e0 = *(const short8*)&Et[il * 64 + (((2 * c) ^ x) << 3)];
            short8 e1 = *(const short8*)&Et[il * 64 + (((2 * c + 1) ^ x) << 3)];
            u16* dst = &P[((long long)(h * NTOK + i0 + il)) * NTOK + j0 + c * 16];
            *(short8*)&dst[0] = e0;
            *(short8*)&dst[8] = e1;
        }
        // PV: A from Et (swizzled), B from Vf; out tile i(64) x d(128)
#pragma unroll
        for (int ks = 0; ks < 2; ks++) {
            short8 a2[2];
#pragma unroll
            for (int m2 = 0; m2 < 2; m2++) {
                int il = wm * 32 + m2 * 16 + l16;
                int ch = ks * 4 + q;
                a2[m2] = *(const short8*)&Et[il * 64 + ((ch ^ (il & 7)) << 3)];
            }
#pragma unroll
            for (int n2 = 0; n2 < 4; n2++) {
                short8 b2 = *(const short8*)&Vf[(((wn * 4 + n2) * 2 + ks) * 64 + lane) * 8];
#pragma unroll
                for (int m2 = 0; m2 < 2; m2++)
                    pv[m2][n2] = __builtin_amdgcn_mfma_f32_16x16x32_bf16(
                        a2[m2], b2, pv[m2][n2], 0, 0, 0);
            }
        }
    }
    // row-sum partials (race-free: one writer per (wn,jc,h,row))
#pragma unroll
    for (int m = 0; m < 2; m++)
#pragma unroll
        for (int r = 0; r < 4; r++) {
            float s = sums[m][r];
            s += __shfl_xor(s, 1);
            s += __shfl_xor(s, 2);
            s += __shfl_xor(s, 4);
            s += __shfl_xor(s, 8);
            if (l16 == 0)
                Spart[((wn * 4 + jc) * NH + h) * NTOK + i0 + wm * 32 + m * 16 + q * 4 + r] = s;
        }
    // store PV partial to this jc's slab (bf16, plain stores, no atomics)
    u16* Xp = Xpart + (long long)jc * NTOK * CDIM;
#pragma unroll
    for (int m2 = 0; m2 < 2; m2++)
#pragma unroll
        for (int n2 = 0; n2 < 4; n2++)
#pragma unroll
            for (int r = 0; r < 4; r++) {
                int i = i0 + wm * 32 + m2 * 16 + q * 4 + r;
                int d = wn * 64 + n2 * 16 + l16;
                Xp[(long long)i * CDIM + h * HD + d] = f2bf(pv[m2][n2][r]);
            }
}

// ---------------------------------------------------------------- K5: x = (sum_jc Xpart)/Srow -> out cols [0,1024)
__global__ __launch_bounds__(256) void k_comb2(const u16* __restrict__ Xpart,
                                               const float* __restrict__ Spart,
                                               float* __restrict__ out) {
    int idx = blockIdx.x * 256 + threadIdx.x;
    int base = idx * 8;
    int i = base >> 10, c = base & 1023;
    int h = c >> 7;
    float s = 0.f;
#pragma unroll
    for (int g = 0; g < 8; g++) s += Spart[(g * NH + h) * NTOK + i];
    float acc[8] = {0.f, 0.f, 0.f, 0.f, 0.f, 0.f, 0.f, 0.f};
#pragma unroll
    for (int jc = 0; jc < 4; jc++) {
        short8 v = *(const short8*)&Xpart[(long long)jc * NTOK * CDIM + (long long)i * CDIM + c];
#pragma unroll
        for (int k = 0; k < 8; k++) acc[k] += bf2f((u16)v[k]);
    }
    float invs = 1.f / s;
    float4 o0, o1;
    o0.x = acc[0] * invs; o0.y = acc[1] * invs; o0.z = acc[2] * invs; o0.w = acc[3] * invs;
    o1.x = acc[4] * invs; o1.y = acc[5] * invs; o1.z = acc[6] * invs; o1.w = acc[7] * invs;
    float* dst = &out[(long long)i * 2048 + c];
    *(float4*)dst = o0;
    *(float4*)(dst + 4) = o1;
}

// ---------------------------------------------------------------- K6: output2 = renormed masked softmax of head-mean attn
__global__ __launch_bounds__(256) void k_out2(const u16* __restrict__ P,
                                              const float* __restrict__ Spart,
                                              const unsigned char* __restrict__ mask,
                                              float* __restrict__ out2) {
    __shared__ float red[256];
    __shared__ float sArr[NH];
    const int i = blockIdx.x;
    const int t = threadIdx.x;
    if (t < NH) {
        float s = 0.f;
#pragma unroll
        for (int g = 0; g < 8; g++) s += Spart[(g * NH + t) * NTOK + i];
        sArr[t] = s;
    }
    __syncthreads();
    float invS[NH];
#pragma unroll
    for (int h = 0; h < NH; h++) invS[h] = 1.f / (8.f * sArr[h]);
    const int c0 = t * 8;
    float a[8] = {0.f, 0.f, 0.f, 0.f, 0.f, 0.f, 0.f, 0.f};
#pragma unroll
    for (int h = 0; h < NH; h++) {
        short8 p = *(const short8*)&P[((long long)h * NTOK + i) * NTOK + c0];
#pragma unroll
        for (int k = 0; k < 8; k++) a[k] += bf2f((u16)p[k]) * invS[h];
    }
    const unsigned char* mrow = mask + (long long)i * NTOK + c0;
    float e[8];
    unsigned char mk[8];
    float part = 0.f;
#pragma unroll
    for (int k = 0; k < 8; k++) {
        e[k] = __expf(a[k]);
        mk[k] = mrow[k];
        if (mk[k]) part += e[k];
    }
    red[t] = part;
    __syncthreads();
    for (int s = 128; s > 0; s >>= 1) {
        if (t < s) red[t] += red[t + s];
        __syncthreads();
    }
    float invT = 1.f / red[0];
    float o[8];
#pragma unroll
    for (int k = 0; k < 8; k++) o[k] = mk[k] ? e[k] * invT : 0.f;
    float4 o0, o1;
    o0.x = o[0]; o0.y = o[1]; o0.z = o[2]; o0.w = o[3];
    o1.x = o[4]; o1.y = o[5]; o1.z = o[6]; o1.w = o[7];
    float* dst = out2 + (long long)i * NTOK + c0;
    *(float4*)dst = o0;
    *(float4*)(dst + 4) = o1;
}

// ---------------------------------------------------------------- launcher
extern "C" void kernel_launch(void* const* d_in, const int* in_sizes, int n_in,
                              void* d_out, int out_size, void* d_ws,
                              size_t ws_size, hipStream_t stream) {
    (void)in_sizes; (void)n_in; (void)out_size; (void)ws_size;
    const float* x = (const float*)d_in[0];
    const float* cls = (const float*)d_in[1];
    // d_in[2] = fg_score: unused by the reference
    const float* Wq = (const float*)d_in[3];
    float* out = (float*)d_out;
    char* ws = (char*)d_ws;

    // Region [0, 23068672): early buffers (Xb/Wb dead after QKV gemm; QKVb dead
    // after k_vt) overlaid with Xpart/Spart (written only by k_attn7 afterwards).
    u16* Xb = (u16*)(ws + 0);                      //  4 MB  [2048,1024]
    u16* Wb = (u16*)(ws + 4194304);                //  6 MB  [3072,1024]
    u16* QKVb = (u16*)(ws + 10485760);             // 12.6MB [2048,3072]
    u16* Xpart = (u16*)(ws + 0);                   // 16 MB  [4][2048,1024] bf16 PV partials
    float* Spart = (float*)(ws + 16777216);        // 512 KB [8][8,2048] row-sum partials
    u16* Qn = (u16*)(ws + 23068672);               //  4 MB
    u16* Kn = (u16*)(ws + 27262976);               //  4 MB
    u16* Vn = (u16*)(ws + 31457280);               //  4 MB
    u16* Vt = (u16*)(ws + 35651584);               //  4 MB  [1024,2048]
    unsigned char* mask = (unsigned char*)(ws + 39845888);  // 4 MB [2048,2048]
    u16* P = (u16*)(ws + 44040192);                // 67 MB [8,2048,2048]

    // 1. cast x and W to bf16
    k_cast<<<1024, 256, 0, stream>>>(x, Wq, Xb, Wb);

    // 2. QKV = Xb @ Wb^T -> bf16 [2048,3072]  (m97-style DMA GEMM)
    k_gemm16<0><<<dim3(C3 / 128, NTOK / 128), 256, 0, stream>>>(
        Xb, Wb, QKVb, CDIM, CDIM, CDIM, C3, 1.f);

    // 3. normalize q/k/v, write x_ori
    k_norm<<<NTOK, 256, 0, stream>>>(QKVb, Qn, Kn, Vn, out);

    // 3b. Vt = v^T (raw v), tiled transpose
    k_vt<<<dim3(NTOK / 64, CDIM / 64), 256, 0, stream>>>(QKVb, Vt);

    // 4. sim mask = (Vn @ Vn^T / 8 > 0.75) -> u8  (m97-style DMA GEMM)
    k_gemm16<1><<<dim3(16, 16), 256, 0, stream>>>(
        Vn, Vn, mask, CDIM, CDIM, CDIM, NTOK, 0.125f);

    // 5. fused logits+exp -> P, partial row sums, partial PV -> Xpart
    k_attn7<<<dim3(32, 4, NH), 256, 0, stream>>>(Qn, Kn, Vt, cls, P, Spart, Xpart);

    // 6. x = (sum Xpart) / (sum Spart)
    k_comb2<<<1024, 256, 0, stream>>>(Xpart, Spart, out);

    // 7. output2
    k_out2<<<NTOK, 256, 0, stream>>>(P, Spart, mask, out + (long long)NTOK * 2048);
}